// Round 2
// baseline (73.833 us; speedup 1.0000x reference)
//
#include <hip/hip_runtime.h>
#include <hip/hip_bf16.h>
#include <stdint.h>

// Embedding TTM order-4:
//   O1[p=225][m=64][c=64]  = sum_{r1<32} U0[0,i0,o0,r1] * U1[r1,i1,o1,c]   (p=i0*15+i1, m=o0*8+o1)
//   O2t[q=225][d=64][c=64] = sum_{r3<32} U2[c,i2,o2,r3] * U3[r3,i3,o3,0]   (q=i2*15+i3, d=o2*8+o3)
//   per element e: row0=x[e]/225, row1=x[e]%225
//   out[e][m][d] = sum_c O1[row0][m][c] * O2t[row1][d][c]   (64x64x64 matmul, MFMA)

typedef __attribute__((ext_vector_type(8))) __bf16 bf16x8;
typedef __attribute__((ext_vector_type(4))) float f32x4;

__device__ inline unsigned short f2bf(float f) {
    union { float f; unsigned u; } v; v.f = f;
    unsigned u = v.u;
    unsigned r = (u + 0x7fffu + ((u >> 16) & 1u)) >> 16;  // RNE
    return (unsigned short)r;
}

// ---------------- build O1[p][m][c] (bf16 bits) ----------------
__global__ __launch_bounds__(256) void build_o1(const float* __restrict__ U0,
                                                const float* __restrict__ U1,
                                                unsigned short* __restrict__ O1) {
    __shared__ float su0[8 * 32];        // [o0][r1]           1 KB
    __shared__ float su1[16 * 8 * 64];   // [r1h][o1][c]       32 KB
    const int p = blockIdx.x;            // 0..224
    const int i0 = p / 15, i1 = p % 15;
    const int t = threadIdx.x;

    // U0 flat (0,i0,o0,r1) = i0*256 + o0*32 + r1;  t = o0*32+r1
    su0[t] = U0[i0 * 256 + t];

    float acc[16];
#pragma unroll
    for (int k = 0; k < 16; ++k) acc[k] = 0.f;

    for (int h = 0; h < 2; ++h) {
        __syncthreads();
        // stage U1 slice for r1 in [h*16, h*16+16): j = r1h*512 + o1*64 + c
        for (int j = t; j < 16 * 8 * 64; j += 256) {
            int r1h = j >> 9, rem = j & 511;          // rem = o1*64 + c
            int r1 = h * 16 + r1h;
            su1[j] = U1[(r1 * 15 + i1) * 512 + rem];
        }
        __syncthreads();
#pragma unroll
        for (int k = 0; k < 16; ++k) {
            int idx = t + k * 256;
            int m = idx >> 6, c = idx & 63;
            int o0 = m >> 3, o1 = m & 7;
            float s = 0.f;
#pragma unroll
            for (int r = 0; r < 16; ++r)
                s += su0[o0 * 32 + h * 16 + r] * su1[r * 512 + o1 * 64 + c];
            acc[k] += s;
        }
    }
#pragma unroll
    for (int k = 0; k < 16; ++k) {
        int idx = t + k * 256;
        O1[p * 4096 + idx] = f2bf(acc[k]);
    }
}

// ---------------- build O2t[q][d][c] (bf16 bits) ----------------
__global__ __launch_bounds__(256) void build_o2(const float* __restrict__ U2,
                                                const float* __restrict__ U3,
                                                unsigned short* __restrict__ O2) {
    __shared__ float su3[32 * 8];        // [r3][o3]           1 KB
    __shared__ float su2[64 * 129];      // [c][o2*16+r3h], padded stride 129 -> ~33 KB
    const int q = blockIdx.x;            // 0..224
    const int i2 = q / 15, i3 = q % 15;
    const int t = threadIdx.x;

    { // t = r3*8 + o3 ;  U3 flat (r3,i3,o3,0) = (r3*15+i3)*8 + o3
        int r3 = t >> 3, o3 = t & 7;
        su3[t] = U3[(r3 * 15 + i3) * 8 + o3];
    }

    float acc[16];
#pragma unroll
    for (int k = 0; k < 16; ++k) acc[k] = 0.f;

    for (int h = 0; h < 2; ++h) {
        __syncthreads();
        // stage U2 slice for r3 in [h*16, h*16+16): j = c*128 + o2*16 + r3h
        for (int j = t; j < 8192; j += 256) {
            int c = j >> 7, o2 = (j >> 4) & 7, r3h = j & 15;
            su2[c * 129 + o2 * 16 + r3h] =
                U2[((c * 15 + i2) * 8 + o2) * 32 + h * 16 + r3h];
        }
        __syncthreads();
#pragma unroll
        for (int k = 0; k < 16; ++k) {
            int idx = t + k * 256;
            int d = idx >> 6, c = idx & 63;
            int o2 = d >> 3, o3 = d & 7;
            float s = 0.f;
#pragma unroll
            for (int r = 0; r < 16; ++r)
                s += su2[c * 129 + o2 * 16 + r] * su3[(h * 16 + r) * 8 + o3];
            acc[k] += s;
        }
    }
#pragma unroll
    for (int k = 0; k < 16; ++k) {
        int idx = t + k * 256;
        O2[q * 4096 + idx] = f2bf(acc[k]);   // [q][d][c]
    }
}

// ---------------- main: per element 64x64x64 MFMA matmul ----------------
__global__ __launch_bounds__(256) void ttm_main(const int* __restrict__ x,
                                                const unsigned short* __restrict__ O1,
                                                const unsigned short* __restrict__ O2,
                                                float* __restrict__ out) {
    const int e = blockIdx.x;
    const unsigned v = (unsigned)x[e];
    const unsigned row0 = v / 225u;
    const unsigned row1 = v % 225u;

    const int t = threadIdx.x;
    const int w = t >> 6;       // wave 0..3 -> C row strip [16w, 16w+16)
    const int l = t & 63;
    const int lr = l & 15;      // fragment row/col
    const int lk = l >> 4;      // k-chunk group

    const unsigned short* Arow = O1 + (size_t)row0 * 4096;  // [m][k], k contiguous
    const unsigned short* Brow = O2 + (size_t)row1 * 4096;  // [d][k], k contiguous

    // A fragments: lane -> A[16w + lr][kk*32 + lk*8 + j]
    bf16x8 a0 = *(const bf16x8*)(Arow + (16 * w + lr) * 64 + 0 * 32 + lk * 8);
    bf16x8 a1 = *(const bf16x8*)(Arow + (16 * w + lr) * 64 + 1 * 32 + lk * 8);

    f32x4 acc[4];
#pragma unroll
    for (int n = 0; n < 4; ++n) acc[n] = (f32x4){0.f, 0.f, 0.f, 0.f};

#pragma unroll
    for (int n = 0; n < 4; ++n) {
        // B fragments: lane -> B[kk*32 + lk*8 + j][n*16 + lr] = O2t[row1][n*16+lr][...]
        bf16x8 b0 = *(const bf16x8*)(Brow + (n * 16 + lr) * 64 + 0 * 32 + lk * 8);
        bf16x8 b1 = *(const bf16x8*)(Brow + (n * 16 + lr) * 64 + 1 * 32 + lk * 8);
        acc[n] = __builtin_amdgcn_mfma_f32_16x16x32_bf16(a0, b0, acc[n], 0, 0, 0);
        acc[n] = __builtin_amdgcn_mfma_f32_16x16x32_bf16(a1, b1, acc[n], 0, 0, 0);
    }

    // D: lane l, reg i = C[(l>>4)*4 + i][l&15]  (within 16x16 frag at (16w, 16n))
    float* Oe = out + (size_t)e * 4096;
#pragma unroll
    for (int n = 0; n < 4; ++n)
#pragma unroll
        for (int i = 0; i < 4; ++i)
            Oe[(16 * w + lk * 4 + i) * 64 + n * 16 + lr] = acc[n][i];
}

extern "C" void kernel_launch(void* const* d_in, const int* in_sizes, int n_in,
                              void* d_out, int out_size, void* d_ws, size_t ws_size,
                              hipStream_t stream) {
    const int* x = (const int*)d_in[0];           // int64 in reference -> int32 in harness
    const float* U0 = (const float*)d_in[1];
    const float* U1 = (const float*)d_in[2];
    const float* U2 = (const float*)d_in[3];
    const float* U3 = (const float*)d_in[4];

    // compact workspace: O1 then O2, each 225*4096*2 B = 1.8432 MB (total 3.6864 MB)
    unsigned short* O1 = (unsigned short*)d_ws;
    unsigned short* O2 = O1 + 225 * 4096;

    const int ne = in_sizes[0];  // 8192 lookups

    build_o1<<<225, 256, 0, stream>>>(U0, U1, O1);
    build_o2<<<225, 256, 0, stream>>>(U2, U3, O2);
    ttm_main<<<ne, 256, 0, stream>>>(x, O1, O2, (float*)d_out);
}

// Round 3
// 55.888 us; speedup vs baseline: 1.3211x; 1.3211x over previous
//
#include <hip/hip_runtime.h>
#include <hip/hip_bf16.h>
#include <stdint.h>

// Embedding TTM order-4:
//   O1[p=225][m=64][c=64]  = sum_{r1<32} U0[0,i0,o0,r1] * U1[r1,i1,o1,c]   (p=i0*15+i1, m=o0*8+o1)
//   O2t[q=225][d=64][c=64] = sum_{r3<32} U2[c,i2,o2,r3] * U3[r3,i3,o3,0]   (q=i2*15+i3, d=o2*8+o3)
//   per element e: row0=x[e]/225, row1=x[e]%225
//   out[e][m][d] = sum_c O1[row0][m][c] * O2t[row1][d][c]
//
// MFMA with SWAPPED operands: D[d][m] = sum_c X[d][c] * Y[c][m],
//   X = O2t row (A-role, rows=d), Y = O1 row (B-role, cols=m).
// D mapping (m89): col = l&15 (=m), row = (l>>4)*4 + reg (=d) -> reg quad holds
// 4 CONSECUTIVE d -> dwordx4 stores into out[e][m][d] (d fast axis).

typedef __attribute__((ext_vector_type(8))) __bf16 bf16x8;
typedef __attribute__((ext_vector_type(4))) float f32x4;

__device__ inline unsigned short f2bf(float f) {
    union { float f; unsigned u; } v; v.f = f;
    unsigned u = v.u;
    unsigned r = (u + 0x7fffu + ((u >> 16) & 1u)) >> 16;  // RNE
    return (unsigned short)r;
}

// ---------------- build O1 and O2t in one launch (450 blocks) ----------------
__global__ __launch_bounds__(256) void build_tables(const float* __restrict__ U0,
                                                    const float* __restrict__ U1,
                                                    const float* __restrict__ U2,
                                                    const float* __restrict__ U3,
                                                    unsigned short* __restrict__ O1,
                                                    unsigned short* __restrict__ O2) {
    __shared__ float smem[8512];   // union of both variants' staging (34 KB)
    const int b = blockIdx.x;
    const int t = threadIdx.x;

    float acc[16];
#pragma unroll
    for (int k = 0; k < 16; ++k) acc[k] = 0.f;

    if (b < 225) {
        // ---- O1[p][m][c], p = b ----
        float* su0 = smem;          // [o0][r1]       256 floats
        float* su1 = smem + 256;    // [r1h][o1][c]   8192 floats
        const int p = b;
        const int i0 = p / 15, i1 = p % 15;

        su0[t] = U0[i0 * 256 + t];   // t = o0*32 + r1

        for (int h = 0; h < 2; ++h) {
            __syncthreads();
            for (int j = t; j < 8192; j += 256) {
                int r1h = j >> 9, rem = j & 511;          // rem = o1*64 + c
                su1[j] = U1[((h * 16 + r1h) * 15 + i1) * 512 + rem];
            }
            __syncthreads();
#pragma unroll
            for (int k = 0; k < 16; ++k) {
                int idx = t + k * 256;
                int m = idx >> 6, c = idx & 63;
                int o0 = m >> 3, o1 = m & 7;
                float s = 0.f;
#pragma unroll
                for (int r = 0; r < 16; ++r)
                    s += su0[o0 * 32 + h * 16 + r] * su1[r * 512 + o1 * 64 + c];
                acc[k] += s;
            }
        }
#pragma unroll
        for (int k = 0; k < 16; ++k)
            O1[p * 4096 + t + k * 256] = f2bf(acc[k]);
    } else {
        // ---- O2t[q][d][c], q = b - 225 ----
        float* su3 = smem;          // [r3][o3]                256 floats
        float* su2 = smem + 256;    // [c][o2*16+r3h] pad 129  8256 floats
        const int q = b - 225;
        const int i2 = q / 15, i3 = q % 15;

        {
            int r3 = t >> 3, o3 = t & 7;
            su3[t] = U3[(r3 * 15 + i3) * 8 + o3];
        }

        for (int h = 0; h < 2; ++h) {
            __syncthreads();
            for (int j = t; j < 8192; j += 256) {
                int c = j >> 7, o2 = (j >> 4) & 7, r3h = j & 15;
                su2[c * 129 + o2 * 16 + r3h] =
                    U2[((c * 15 + i2) * 8 + o2) * 32 + h * 16 + r3h];
            }
            __syncthreads();
#pragma unroll
            for (int k = 0; k < 16; ++k) {
                int idx = t + k * 256;
                int d = idx >> 6, c = idx & 63;
                int o2 = d >> 3, o3 = d & 7;
                float s = 0.f;
#pragma unroll
                for (int r = 0; r < 16; ++r)
                    s += su2[c * 129 + o2 * 16 + r] * su3[(h * 16 + r) * 8 + o3];
                acc[k] += s;
            }
        }
#pragma unroll
        for (int k = 0; k < 16; ++k)
            O2[q * 4096 + t + k * 256] = f2bf(acc[k]);   // [q][d][c]
    }
}

// ---------------- main: one element per wave, 4 per block ----------------
__global__ __launch_bounds__(256) void ttm_main(const int* __restrict__ x,
                                                const unsigned short* __restrict__ O1,
                                                const unsigned short* __restrict__ O2,
                                                float* __restrict__ out, int ne) {
    const int w = threadIdx.x >> 6;
    const int l = threadIdx.x & 63;
    const int e = blockIdx.x * 4 + w;
    if (e >= ne) return;

    const unsigned v = (unsigned)x[e];
    const unsigned row0 = v / 225u;
    const unsigned row1 = v - row0 * 225u;

    const int lr = l & 15;   // fragment row/col index
    const int lk = l >> 4;   // k-chunk group

    const unsigned short* Yp = O1 + (size_t)row0 * 4096;  // [m][c], c contiguous
    const unsigned short* Xp = O2 + (size_t)row1 * 4096;  // [d][c], c contiguous

    // B-role fragments from O1: Y[mq][h] -> Y[c = h*32+lk*8+j][m = 16mq+lr]
    bf16x8 Y[4][2];
#pragma unroll
    for (int mq = 0; mq < 4; ++mq)
#pragma unroll
        for (int h = 0; h < 2; ++h)
            Y[mq][h] = *(const bf16x8*)(Yp + (16 * mq + lr) * 64 + h * 32 + lk * 8);

    float* Oe = out + (size_t)e * 4096;

#pragma unroll
    for (int nq = 0; nq < 4; ++nq) {
        // A-role fragments from O2t: X[d = 16nq+lr][c = h*32+lk*8+j]
        bf16x8 X0 = *(const bf16x8*)(Xp + (16 * nq + lr) * 64 + 0 * 32 + lk * 8);
        bf16x8 X1 = *(const bf16x8*)(Xp + (16 * nq + lr) * 64 + 1 * 32 + lk * 8);

        f32x4 acc[4];
#pragma unroll
        for (int mq = 0; mq < 4; ++mq) acc[mq] = (f32x4){0.f, 0.f, 0.f, 0.f};

#pragma unroll
        for (int mq = 0; mq < 4; ++mq) {
            acc[mq] = __builtin_amdgcn_mfma_f32_16x16x32_bf16(X0, Y[mq][0], acc[mq], 0, 0, 0);
            acc[mq] = __builtin_amdgcn_mfma_f32_16x16x32_bf16(X1, Y[mq][1], acc[mq], 0, 0, 0);
        }

        // D[d][m]: lane l, reg i -> d = 16nq + lk*4 + i, m = 16mq + lr
        // store f32x4 at out[e][m][16nq + lk*4 .. +3]
#pragma unroll
        for (int mq = 0; mq < 4; ++mq) {
            f32x4* p = (f32x4*)(Oe + (16 * mq + lr) * 64 + 16 * nq + lk * 4);
            __builtin_nontemporal_store(acc[mq], p);
        }
    }
}

extern "C" void kernel_launch(void* const* d_in, const int* in_sizes, int n_in,
                              void* d_out, int out_size, void* d_ws, size_t ws_size,
                              hipStream_t stream) {
    const int* x = (const int*)d_in[0];           // int64 in reference -> int32 in harness
    const float* U0 = (const float*)d_in[1];
    const float* U1 = (const float*)d_in[2];
    const float* U2 = (const float*)d_in[3];
    const float* U3 = (const float*)d_in[4];

    unsigned short* O1 = (unsigned short*)d_ws;       // 225*4096*2 = 1.8432 MB
    unsigned short* O2 = O1 + 225 * 4096;             // 1.8432 MB

    const int ne = in_sizes[0];  // 8192 lookups

    build_tables<<<450, 256, 0, stream>>>(U0, U1, U2, U3, O1, O2);
    ttm_main<<<(ne + 3) / 4, 256, 0, stream>>>(x, O1, O2, (float*)d_out, ne);
}